// Round 17
// baseline (97.158 us; speedup 1.0000x reference)
//
#include <hip/hip_runtime.h>
#include <hip/hip_bf16.h>

// ---------------------------------------------------------------------------
// Fused attention: x@Wqkv -> q,k,v ; flash split-KV attention over
// concat(past_k, k_new) ; combine ; @Wproj -> out.
// B=2, N=256, DIM=1024, H=16, D=64, L=8192, total keys 8448 = 132 x 64.
// R17: prefetch depth 2. attn streams 134MB at only 2.2 TB/s with no pipe
// saturated; remaining live theory is load-latency under-coverage (loads in
// flight <1 iteration). Dual named register sets E/O: at iter it, stage
// step it+1 from the set loaded two iters ago, then issue load(it+3) into
// it -> ~2 iterations of latency cover, 2x outstanding bytes. Rule-#20-safe
// (all static indexing). Rest = R16 (best: pipelined GEMMs, R14 attn core).
// ---------------------------------------------------------------------------

#define BB 2
#define NH 16
#define NQ 256
#define HD 64
#define DIMC 1024
#define LPAST 8192
#define TOTK 8448
#define NSPLIT 16
// 132 steps of 64 keys: splits 0..3 take 9 steps, 4..15 take 8.
// Steps 128..131 (inside split 15) read knew/vnew; selected per step.

typedef __attribute__((ext_vector_type(8))) short short8;
typedef __attribute__((ext_vector_type(4))) float f32x4;
typedef __attribute__((ext_vector_type(16))) float f32x16;
typedef __attribute__((ext_vector_type(4))) int int4v;

#define DEVI static __device__ __forceinline__

DEVI float exp2g(float x) { return __builtin_amdgcn_exp2f(x); }  // v_exp_f32

DEVI int cvtpk(float lo, float hi) {     // dword = {bf16(lo), bf16(hi)}
  int r;
  asm("v_cvt_pk_bf16_f32 %0, %1, %2" : "=v"(r) : "v"(lo), "v"(hi));
  return r;
}
DEVI short f2bf(float f) {               // scalar f32 -> bf16 (RNE)
  union { float f; unsigned u; } v; v.f = f;
  unsigned r = v.u + 0x7FFFu + ((v.u >> 16) & 1u);
  return (short)(r >> 16);
}
// Barrier that does NOT drain vmcnt: LDS-only ordering (T4).
DEVI void ldsbar() {
  asm volatile("s_waitcnt lgkmcnt(0)" ::: "memory");
  __builtin_amdgcn_s_barrier();
}

// ---------------------------------------------------------------------------
// 64x64-tile bf16 MFMA GEMM, f32 inputs converted during staging.
// Double-buffered LDS, one ldsbar per K-step, loads 2 steps ahead (R16).
// MODE 0: Cout[row*Nn+col] = acc + bias[col]
// MODE 1: scatter into q (bf16, *0.125*log2e), k_new, v_new  [B,H,N,D]
// ---------------------------------------------------------------------------
template<int MODE>
__global__ __launch_bounds__(256, 2) void gemm_k(
    const float* __restrict__ A, const float* __restrict__ Bm,
    const float* __restrict__ bias, float* __restrict__ Cout,
    short* __restrict__ qbuf, float* __restrict__ knew, float* __restrict__ vnew,
    int M, int Nn, int K)
{
  __shared__ alignas(16) short As[2][64][72];   // [buf][m][k] bf16, +8 pad
  __shared__ alignas(16) short Bs[2][64][72];   // [buf][n][k] bf16 (B transposed)
  const int tid = threadIdx.x;
  const int lane = tid & 63, wave = tid >> 6;
  const int nblk = Nn >> 6;
  const int bi = blockIdx.x / nblk, bj = blockIdx.x % nblk;
  const int wm = wave >> 1, wn = wave & 1;
  const int g = lane >> 4, l16 = lane & 15;
  f32x4 acc[2][2] = {};
  const int r = tid >> 2, q4 = (tid & 3) << 4;

  float4 a0, a1, a2, a3, b0, b1, b2, b3;
  auto loadk = [&](int k0) {
    const float* pa = A + (size_t)(bi * 64 + r) * K + (k0 + q4);
    a0 = ((const float4*)pa)[0];
    a1 = ((const float4*)pa)[1];
    a2 = ((const float4*)pa)[2];
    a3 = ((const float4*)pa)[3];
    const float* pb = Bm + (size_t)(k0 + r) * Nn + (bj * 64 + q4);
    b0 = ((const float4*)pb)[0];
    b1 = ((const float4*)pb)[1];
    b2 = ((const float4*)pb)[2];
    b3 = ((const float4*)pb)[3];
  };
  auto stagek = [&](int buf) {
    int4v p0 = {cvtpk(a0.x,a0.y), cvtpk(a0.z,a0.w), cvtpk(a1.x,a1.y), cvtpk(a1.z,a1.w)};
    int4v p1 = {cvtpk(a2.x,a2.y), cvtpk(a2.z,a2.w), cvtpk(a3.x,a3.y), cvtpk(a3.z,a3.w)};
    *(int4v*)&As[buf][r][q4]     = p0;
    *(int4v*)&As[buf][r][q4 + 8] = p1;
    Bs[buf][q4+ 0][r] = f2bf(b0.x); Bs[buf][q4+ 1][r] = f2bf(b0.y);
    Bs[buf][q4+ 2][r] = f2bf(b0.z); Bs[buf][q4+ 3][r] = f2bf(b0.w);
    Bs[buf][q4+ 4][r] = f2bf(b1.x); Bs[buf][q4+ 5][r] = f2bf(b1.y);
    Bs[buf][q4+ 6][r] = f2bf(b1.z); Bs[buf][q4+ 7][r] = f2bf(b1.w);
    Bs[buf][q4+ 8][r] = f2bf(b2.x); Bs[buf][q4+ 9][r] = f2bf(b2.y);
    Bs[buf][q4+10][r] = f2bf(b2.z); Bs[buf][q4+11][r] = f2bf(b2.w);
    Bs[buf][q4+12][r] = f2bf(b3.x); Bs[buf][q4+13][r] = f2bf(b3.y);
    Bs[buf][q4+14][r] = f2bf(b3.z); Bs[buf][q4+15][r] = f2bf(b3.w);
  };

  const int nk = K >> 6;
  loadk(0);
  stagek(0);
  if (nk > 1) loadk(64);
  ldsbar();

  for (int ki = 0; ki < nk; ++ki) {
    const int cur = ki & 1;
    #pragma unroll
    for (int kf = 0; kf < 2; ++kf) {
      short8 af[2], bfv[2];
      #pragma unroll
      for (int mt = 0; mt < 2; ++mt)
        af[mt] = *(const short8*)&As[cur][wm*32 + mt*16 + l16][kf*32 + g*8];
      #pragma unroll
      for (int nt = 0; nt < 2; ++nt)
        bfv[nt] = *(const short8*)&Bs[cur][wn*32 + nt*16 + l16][kf*32 + g*8];
      #pragma unroll
      for (int mt = 0; mt < 2; ++mt)
        #pragma unroll
        for (int nt = 0; nt < 2; ++nt)
          acc[mt][nt] = __builtin_amdgcn_mfma_f32_16x16x32_bf16(
              af[mt], bfv[nt], acc[mt][nt], 0, 0, 0);
    }
    if (ki + 1 < nk) {
      stagek(1 - cur);
      if (ki + 2 < nk) loadk((ki + 2) << 6);
      ldsbar();
    }
  }

  #pragma unroll
  for (int mt = 0; mt < 2; ++mt)
    #pragma unroll
    for (int nt = 0; nt < 2; ++nt)
      #pragma unroll
      for (int rg = 0; rg < 4; ++rg) {
        int row = bi*64 + wm*32 + mt*16 + g*4 + rg;
        int col = bj*64 + wn*32 + nt*16 + l16;
        float val = acc[mt][nt][rg] + bias[col];
        if (MODE == 0) {
          Cout[(size_t)row * Nn + col] = val;
        } else {
          int which = col >> 10, cc = col & 1023;
          int h = cc >> 6, d = cc & 63;
          int b = row >> 8, n = row & 255;
          size_t idx = (((size_t)(b*NH + h))*NQ + n)*HD + d;
          if (which == 0)      qbuf[idx] = f2bf(val * 0.180336878f); // 0.125*log2(e)
          else if (which == 1) knew[idx] = val;
          else                 vnew[idx] = val;
        }
      }
}

// ---------------------------------------------------------------------------
// Flash attention, split-KV, swapped-QK in-register softmax (exp2 domain).
// Grid: (B*H)*NSPLIT blocks, 256 threads = 4 waves x 64 queries each.
// R17 pipeline, per iteration it: [QK(it) || PV(it-1)] MFMA cluster ->
// stage(it+1) from set (E if it even, O if odd) -> load(it+3) into that
// set -> softmax(it)+pack -> ldsbar.  K buf = it&1, V buf = it%3.
// ---------------------------------------------------------------------------
__global__ __launch_bounds__(256, 2) void attn_k(
    const short* __restrict__ qbuf, const float* __restrict__ pastk,
    const float* __restrict__ pastv, const float* __restrict__ knew,
    const float* __restrict__ vnew, _Float16* __restrict__ opart,
    float* __restrict__ mbuf, float* __restrict__ lbuf)
{
  __shared__ alignas(16) short Kt[2][64][64];   // [buf][key][d], swizzled
  __shared__ alignas(16) short Vt[3][64][64];   // [buf][d][pi(key)], swizzled
  const int tid = threadIdx.x;
  const int lane = tid & 63, qg = tid >> 6;        // query group 0..3
  const int h = lane >> 5, c = lane & 31;
  const int s = blockIdx.x & (NSPLIT - 1), bh = blockIdx.x / NSPLIT;
  const int kr = tid >> 2, kd16 = (tid & 3) << 4;  // K staging: key kr, d kd16..+15
  const int vq2 = tid & 31, dg = tid >> 5;         // V staging: keys 2vq2,2vq2+1; d[8dg,+8)
  const int key0 = 2 * vq2;
  const int vpi = ((key0>>5)<<5) | (((key0>>3)&1)<<4) | (((key0>>2)&1)<<3)
                | (((key0>>4)&1)<<2) | (key0&3);   // pi(key0), even
  const int csw = (c & 7) << 3;                    // read-side swizzle term

  // Q fragments: lane holds Q[q][d = 16*dk + 8h + 0..7] for both tiles
  short8 qfA[4], qfB[4];
  #pragma unroll
  for (int dk = 0; dk < 4; ++dk) {
    qfA[dk] = *(const short8*)(qbuf + ((size_t)bh*NQ + qg*64 + c)*HD + 16*dk + 8*h);
    qfB[dk] = *(const short8*)(qbuf + ((size_t)bh*NQ + qg*64 + 32 + c)*HD + 16*dk + 8*h);
  }

  f32x16 accA[2] = {}, accB[2] = {};  // [dt]: O[q=rr][d=32*dt+c]
  float mA = -INFINITY, lA = 0.f, mB = -INFINITY, lB = 0.f;  // l = half-sums
  short8 paA[4], paB[4];              // P fragments of the PREVIOUS tile

  const int first  = 8*s + (s < 4 ? s : 4);
  const int nsteps = 8 + (s < 4 ? 1 : 0);

  // two prefetch register sets (E = even iters, O = odd iters)
  float kstE[16], vArE[8], vBrE[8];
  float kstO[16], vArO[8], vBrO[8];

  auto loadE = [&](int step) {
    const float* kp = (step < 128)
        ? pastk + ((size_t)bh*LPAST + step*64 + kr)*HD + kd16
        : knew  + ((size_t)bh*NQ + (step - 128)*64 + kr)*HD + kd16;
    *(float4*)&kstE[0]  = ((const float4*)kp)[0];
    *(float4*)&kstE[4]  = ((const float4*)kp)[1];
    *(float4*)&kstE[8]  = ((const float4*)kp)[2];
    *(float4*)&kstE[12] = ((const float4*)kp)[3];
    const float* vq = (step < 128)
        ? pastv + ((size_t)bh*LPAST + step*64 + key0)*HD + 8*dg
        : vnew  + ((size_t)bh*NQ + (step - 128)*64 + key0)*HD + 8*dg;
    *(float4*)&vArE[0] = ((const float4*)vq)[0];
    *(float4*)&vArE[4] = ((const float4*)vq)[1];
    *(float4*)&vBrE[0] = ((const float4*)(vq + HD))[0];
    *(float4*)&vBrE[4] = ((const float4*)(vq + HD))[1];
  };
  auto loadO = [&](int step) {
    const float* kp = (step < 128)
        ? pastk + ((size_t)bh*LPAST + step*64 + kr)*HD + kd16
        : knew  + ((size_t)bh*NQ + (step - 128)*64 + kr)*HD + kd16;
    *(float4*)&kstO[0]  = ((const float4*)kp)[0];
    *(float4*)&kstO[4]  = ((const float4*)kp)[1];
    *(float4*)&kstO[8]  = ((const float4*)kp)[2];
    *(float4*)&kstO[12] = ((const float4*)kp)[3];
    const float* vq = (step < 128)
        ? pastv + ((size_t)bh*LPAST + step*64 + key0)*HD + 8*dg
        : vnew  + ((size_t)bh*NQ + (step - 128)*64 + key0)*HD + 8*dg;
    *(float4*)&vArO[0] = ((const float4*)vq)[0];
    *(float4*)&vArO[4] = ((const float4*)vq)[1];
    *(float4*)&vBrO[0] = ((const float4*)(vq + HD))[0];
    *(float4*)&vBrO[4] = ((const float4*)(vq + HD))[1];
  };
  auto stageE = [&](int it2) {     // stage tile it2 into Kt[it2&1], Vt[it2%3]
    int kb = it2 & 1, vb = it2 % 3;
    int4v k0 = {cvtpk(kstE[0],kstE[1]),  cvtpk(kstE[2],kstE[3]),
                cvtpk(kstE[4],kstE[5]),  cvtpk(kstE[6],kstE[7])};
    int4v k1 = {cvtpk(kstE[8],kstE[9]),  cvtpk(kstE[10],kstE[11]),
                cvtpk(kstE[12],kstE[13]), cvtpk(kstE[14],kstE[15])};
    *(int4v*)&Kt[kb][kr][kd16 ^ ((kr & 7) << 3)]       = k0;
    *(int4v*)&Kt[kb][kr][(kd16 + 8) ^ ((kr & 7) << 3)] = k1;
    #pragma unroll
    for (int i = 0; i < 8; ++i) {
      int row = 8*dg + i;                            // row&7 == i
      *(int*)&Vt[vb][row][vpi ^ (i << 3)] = cvtpk(vArE[i], vBrE[i]);
    }
  };
  auto stageO = [&](int it2) {
    int kb = it2 & 1, vb = it2 % 3;
    int4v k0 = {cvtpk(kstO[0],kstO[1]),  cvtpk(kstO[2],kstO[3]),
                cvtpk(kstO[4],kstO[5]),  cvtpk(kstO[6],kstO[7])};
    int4v k1 = {cvtpk(kstO[8],kstO[9]),  cvtpk(kstO[10],kstO[11]),
                cvtpk(kstO[12],kstO[13]), cvtpk(kstO[14],kstO[15])};
    *(int4v*)&Kt[kb][kr][kd16 ^ ((kr & 7) << 3)]       = k0;
    *(int4v*)&Kt[kb][kr][(kd16 + 8) ^ ((kr & 7) << 3)] = k1;
    #pragma unroll
    for (int i = 0; i < 8; ++i) {
      int row = 8*dg + i;
      *(int*)&Vt[vb][row][vpi ^ (i << 3)] = cvtpk(vArO[i], vBrO[i]);
    }
  };

  // Prologue: E holds first+1 (after staging first), O holds first+2.
  loadE(first);
  stageE(0);
  loadE(first + 1);
  loadO(first + 2);
  ldsbar();

  for (int it = 0; it < nsteps; ++it) {
    const int kb = it & 1;

    // ---- merged MFMA cluster: QK(it) and deferred PV(it-1), all independent
    f32x16 svA0 = {}, svA1 = {}, svB0 = {}, svB1 = {};
    __builtin_amdgcn_s_setprio(1);
    if (it > 0) {
      const int pvb = (it - 1) % 3;
      #pragma unroll
      for (int kc = 0; kc < 4; ++kc) {
        #pragma unroll
        for (int dt = 0; dt < 2; ++dt) {
          short8 vf = *(const short8*)&Vt[pvb][32*dt + c][(16*kc + 8*h) ^ csw];
          accA[dt] = __builtin_amdgcn_mfma_f32_32x32x16_bf16(paA[kc], vf, accA[dt], 0,0,0);
          accB[dt] = __builtin_amdgcn_mfma_f32_32x32x16_bf16(paB[kc], vf, accB[dt], 0,0,0);
        }
      }
    }
    #pragma unroll
    for (int dk = 0; dk < 4; ++dk) {
      short8 k0 = *(const short8*)&Kt[kb][c][(16*dk + 8*h) ^ csw];
      svA0 = __builtin_amdgcn_mfma_f32_32x32x16_bf16(k0, qfA[dk], svA0, 0,0,0);
      svB0 = __builtin_amdgcn_mfma_f32_32x32x16_bf16(k0, qfB[dk], svB0, 0,0,0);
    }
    #pragma unroll
    for (int dk = 0; dk < 4; ++dk) {
      short8 k1 = *(const short8*)&Kt[kb][32 + c][(16*dk + 8*h) ^ csw];
      svA1 = __builtin_amdgcn_mfma_f32_32x32x16_bf16(k1, qfA[dk], svA1, 0,0,0);
      svB1 = __builtin_amdgcn_mfma_f32_32x32x16_bf16(k1, qfB[dk], svB1, 0,0,0);
    }
    __builtin_amdgcn_s_setprio(0);

    // ---- stage tile it+1 from the set loaded 2 iterations ago, then refill
    // that set with the load for it+3 (2-deep prefetch, T14-style).
    if (it + 1 < nsteps) {
      if ((it & 1) == 0) {
        stageE(it + 1);
        if (it + 3 < nsteps) loadE(first + it + 3);
      } else {
        stageO(it + 1);
        if (it + 3 < nsteps) loadO(first + it + 3);
      }
    }

    // ---- softmax tile A (rescale covers the just-landed PV(it-1)) ----
    {
      float t16[16];
      #pragma unroll
      for (int r = 0; r < 16; ++r) t16[r] = fmaxf(svA0[r], svA1[r]);
      #pragma unroll
      for (int w = 8; w >= 1; w >>= 1)
        #pragma unroll
        for (int r = 0; r < w; ++r) t16[r] = fmaxf(t16[r], t16[r + w]);
      if (!__all(t16[0] <= mA + 8.f)) {   // T13 defer-max
        float mx = fmaxf(t16[0], __shfl_xor(t16[0], 32));
        float mn = fmaxf(mA, mx);
        float al = exp2g(mA - mn);
        lA *= al;
        #pragma unroll
        for (int r = 0; r < 16; ++r) {
          float a = __shfl(al, (r&3) + 8*(r>>2) + 4*h);
          accA[0][r] *= a; accA[1][r] *= a;
        }
        mA = mn;
      }
      float ss = 0.f;
      #pragma unroll
      for (int r = 0; r < 16; ++r) {
        float p0 = exp2g(svA0[r] - mA); svA0[r] = p0;
        float p1 = exp2g(svA1[r] - mA); svA1[r] = p1;
        ss += p0 + p1;
      }
      lA += ss;
      #pragma unroll
      for (int kc = 0; kc < 4; ++kc) {
        int4v w;
        #pragma unroll
        for (int jd = 0; jd < 4; ++jd) {
          int r0 = 8*(jd>>1) + 4*(kc&1) + 2*(jd&1);
          w[jd] = (kc < 2) ? cvtpk(svA0[r0], svA0[r0+1])
                           : cvtpk(svA1[r0], svA1[r0+1]);
        }
        paA[kc] = __builtin_bit_cast(short8, w);
      }
    }
    // ---- softmax tile B ----
    {
      float t16[16];
      #pragma unroll
      for (int r = 0; r < 16; ++r) t16[r] = fmaxf(svB0[r], svB1[r]);
      #pragma unroll
      for (int w = 8; w >= 1; w >>= 1)
        #pragma unroll
        for (int r = 0; r < w; ++r) t16[r] = fmaxf(t16[r], t16[r + w]);
      if (!__all(t16[0] <= mB + 8.f)) {
        float mx = fmaxf(t16[0], __shfl_xor(t16[0], 32));
        float mn = fmaxf(mB, mx);
        float al = exp2g(mB - mn);
        lB *= al;
        #pragma unroll
        for (int r = 0; r < 16; ++r) {
          float a = __shfl(al, (r&3) + 8*(r>>2) + 4*h);
          accB[0][r] *= a; accB[1][r] *= a;
        }
        mB = mn;
      }
      float ss = 0.f;
      #pragma unroll
      for (int r = 0; r < 16; ++r) {
        float p0 = exp2g(svB0[r] - mB); svB0[r] = p0;
        float p1 = exp2g(svB1[r] - mB); svB1[r] = p1;
        ss += p0 + p1;
      }
      lB += ss;
      #pragma unroll
      for (int kc = 0; kc < 4; ++kc) {
        int4v w;
        #pragma unroll
        for (int jd = 0; jd < 4; ++jd) {
          int r0 = 8*(jd>>1) + 4*(kc&1) + 2*(jd&1);
          w[jd] = (kc < 2) ? cvtpk(svB0[r0], svB0[r0+1])
                           : cvtpk(svB1[r0], svB1[r0+1]);
        }
        paB[kc] = __builtin_bit_cast(short8, w);
      }
    }

    if (it + 1 < nsteps) ldsbar();
  }

  // ---- epilogue: final deferred PV for tile nsteps-1
  {
    const int pvb = (nsteps - 1) % 3;
    #pragma unroll
    for (int kc = 0; kc < 4; ++kc) {
      #pragma unroll
      for (int dt = 0; dt < 2; ++dt) {
        short8 vf = *(const short8*)&Vt[pvb][32*dt + c][(16*kc + 8*h) ^ csw];
        accA[dt] = __builtin_amdgcn_mfma_f32_32x32x16_bf16(paA[kc], vf, accA[dt], 0,0,0);
        accB[dt] = __builtin_amdgcn_mfma_f32_32x32x16_bf16(paB[kc], vf, accB[dt], 0,0,0);
      }
    }
  }

  // Write NORMALIZED partials (o/l as f16). acc[dt][r] is query rr's row, so
  // fetch that query's reciprocal from lane rr (R12 fix).
  float lAt = lA + __shfl_xor(lA, 32);
  float lBt = lB + __shfl_xor(lB, 32);
  float rA = 1.0f / lAt, rB = 1.0f / lBt;
  size_t pbase = ((size_t)(bh * NSPLIT + s)) * NQ;
  #pragma unroll
  for (int r = 0; r < 16; ++r) {
    int rr = (r&3) + 8*(r>>2) + 4*h;
    float rAr = __shfl(rA, rr);     // lane rr owns query rr's l (tile A)
    float rBr = __shfl(rB, rr);     // lane rr owns query 32+rr's l (tile B)
    #pragma unroll
    for (int dt = 0; dt < 2; ++dt) {
      opart[(pbase + qg*64 + rr)*HD + 32*dt + c]      = (_Float16)(accA[dt][r] * rAr);
      opart[(pbase + qg*64 + 32 + rr)*HD + 32*dt + c] = (_Float16)(accB[dt][r] * rBr);
    }
  }
  if (lane < 32) {
    mbuf[pbase + qg*64 + c]      = mA;
    lbuf[pbase + qg*64 + c]      = lAt;
    mbuf[pbase + qg*64 + 32 + c] = mB;
    lbuf[pbase + qg*64 + 32 + c] = lBt;
  }
}

// ---------------------------------------------------------------------------
// Combine NSPLIT partials per (b,h,n); write attn output [B,N,DIM] f32.
// Partials are normalized (o/l), so weight = l * 2^(m-M).
// ---------------------------------------------------------------------------
__global__ __launch_bounds__(256) void combine_k(
    const _Float16* __restrict__ opart, const float* __restrict__ mbuf,
    const float* __restrict__ lbuf, float* __restrict__ attnout)
{
  const int lane = threadIdx.x & 63, wave = threadIdx.x >> 6;
  const int rid = blockIdx.x * 4 + wave;   // 0 .. B*H*N-1
  const int bh = rid >> 8, n = rid & 255;
  const int b = bh >> 4, h = bh & 15;
  float M = -INFINITY;
  float ms[NSPLIT], ls[NSPLIT];
  #pragma unroll
  for (int s = 0; s < NSPLIT; ++s) {
    size_t base = ((size_t)(bh * NSPLIT + s)) * NQ + n;
    ms[s] = mbuf[base]; ls[s] = lbuf[base];
    M = fmaxf(M, ms[s]);
  }
  float denom = 0.f, o = 0.f;
  #pragma unroll
  for (int s = 0; s < NSPLIT; ++s) {
    float w = exp2g(ms[s] - M) * ls[s];
    denom += w;
    o += w * (float)opart[(((size_t)(bh * NSPLIT + s)) * NQ + n) * HD + lane];
  }
  attnout[((size_t)(b * NQ + n)) * DIMC + h * HD + lane] = o / denom;
}

// ---------------------------------------------------------------------------
extern "C" void kernel_launch(void* const* d_in, const int* in_sizes, int n_in,
                              void* d_out, int out_size, void* d_ws, size_t ws_size,
                              hipStream_t stream)
{
  const float* x     = (const float*)d_in[0];
  const float* pastk = (const float*)d_in[1];
  const float* pastv = (const float*)d_in[2];
  const float* wqkv  = (const float*)d_in[3];
  const float* bqkv  = (const float*)d_in[4];
  const float* wproj = (const float*)d_in[5];
  const float* bproj = (const float*)d_in[6];
  float* out = (float*)d_out;
  char* ws = (char*)d_ws;

  size_t off = 0;
  short* qbuf     = (short*)(ws + off);     off += (size_t)BB*NH*NQ*HD*2;          // 1MB
  float* knew     = (float*)(ws + off);     off += (size_t)BB*NH*NQ*HD*4;          // 2MB
  float* vnew     = (float*)(ws + off);     off += (size_t)BB*NH*NQ*HD*4;          // 2MB
  _Float16* opart = (_Float16*)(ws + off);  off += (size_t)BB*NH*NSPLIT*NQ*HD*2;   // 16.8MB
  float* mbuf     = (float*)(ws + off);     off += (size_t)BB*NH*NSPLIT*NQ*4;      // 512KB
  float* lbuf     = (float*)(ws + off);     off += (size_t)BB*NH*NSPLIT*NQ*4;      // 512KB
  float* attnout  = (float*)(ws + off);     off += (size_t)BB*NQ*DIMC*4;           // 2MB

  // 1) QKV projection: [512,1024] x [1024,3072]
  gemm_k<1><<<(512/64)*(3072/64), 256, 0, stream>>>(
      x, wqkv, bqkv, nullptr, qbuf, knew, vnew, 512, 3072, 1024);
  // 2) split-KV flash attention
  attn_k<<<BB*NH*NSPLIT, 256, 0, stream>>>(
      qbuf, pastk, pastv, knew, vnew, opart, mbuf, lbuf);
  // 3) combine partials
  combine_k<<<BB*NH*NQ/4, 256, 0, stream>>>(opart, mbuf, lbuf, attnout);
  // 4) output projection: [512,1024] x [1024,1024]
  gemm_k<0><<<(512/64)*(1024/64), 256, 0, stream>>>(
      attnout, wproj, bproj, out, nullptr, nullptr, nullptr, 512, 1024, 1024);
}

// Round 18
// 74.780 us; speedup vs baseline: 1.2993x; 1.2993x over previous
//
#include <hip/hip_runtime.h>
#include <hip/hip_bf16.h>

// ---------------------------------------------------------------------------
// Fused attention: x@Wqkv -> q,k,v ; flash split-KV attention over
// concat(past_k, k_new) ; combine ; @Wproj -> out.
// B=2, N=256, DIM=1024, H=16, D=64, L=8192, total keys 8448 = 132 x 64.
// R18: revert attn to R16/R14 core (best: 76.9us total; R17's 2-deep
// prefetch spilled -- WRITE 68MB). One safe cut: combine_k writes attnout as
// bf16 (the proj GEMM converted A to bf16 anyway -- identical numerics), and
// the output projection uses gemm0_k with bf16-A staging (two short8 copies,
// no cvtpk, half the A traffic).
// ---------------------------------------------------------------------------

#define BB 2
#define NH 16
#define NQ 256
#define HD 64
#define DIMC 1024
#define LPAST 8192
#define TOTK 8448
#define NSPLIT 16
// 132 steps of 64 keys: splits 0..3 take 9 steps, 4..15 take 8.
// Steps 128..131 (inside split 15) read knew/vnew; selected per step.

typedef __attribute__((ext_vector_type(8))) short short8;
typedef __attribute__((ext_vector_type(4))) float f32x4;
typedef __attribute__((ext_vector_type(16))) float f32x16;
typedef __attribute__((ext_vector_type(4))) int int4v;

#define DEVI static __device__ __forceinline__

DEVI float exp2g(float x) { return __builtin_amdgcn_exp2f(x); }  // v_exp_f32

DEVI int cvtpk(float lo, float hi) {     // dword = {bf16(lo), bf16(hi)}
  int r;
  asm("v_cvt_pk_bf16_f32 %0, %1, %2" : "=v"(r) : "v"(lo), "v"(hi));
  return r;
}
DEVI short f2bf(float f) {               // scalar f32 -> bf16 (RNE)
  union { float f; unsigned u; } v; v.f = f;
  unsigned r = v.u + 0x7FFFu + ((v.u >> 16) & 1u);
  return (short)(r >> 16);
}
// Barrier that does NOT drain vmcnt: LDS-only ordering (T4).
DEVI void ldsbar() {
  asm volatile("s_waitcnt lgkmcnt(0)" ::: "memory");
  __builtin_amdgcn_s_barrier();
}

// ---------------------------------------------------------------------------
// 64x64-tile bf16 MFMA GEMM, f32 inputs converted during staging (QKV).
// Double-buffered LDS, one ldsbar per K-step, loads 2 steps ahead.
// Scatters into q (bf16, *0.125*log2e), k_new, v_new  [B,H,N,D].
// ---------------------------------------------------------------------------
__global__ __launch_bounds__(256, 2) void gemm_k(
    const float* __restrict__ A, const float* __restrict__ Bm,
    const float* __restrict__ bias,
    short* __restrict__ qbuf, float* __restrict__ knew, float* __restrict__ vnew,
    int M, int Nn, int K)
{
  __shared__ alignas(16) short As[2][64][72];   // [buf][m][k] bf16, +8 pad
  __shared__ alignas(16) short Bs[2][64][72];   // [buf][n][k] bf16 (B transposed)
  const int tid = threadIdx.x;
  const int lane = tid & 63, wave = tid >> 6;
  const int nblk = Nn >> 6;
  const int bi = blockIdx.x / nblk, bj = blockIdx.x % nblk;
  const int wm = wave >> 1, wn = wave & 1;
  const int g = lane >> 4, l16 = lane & 15;
  f32x4 acc[2][2] = {};
  const int r = tid >> 2, q4 = (tid & 3) << 4;

  float4 a0, a1, a2, a3, b0, b1, b2, b3;
  auto loadk = [&](int k0) {
    const float* pa = A + (size_t)(bi * 64 + r) * K + (k0 + q4);
    a0 = ((const float4*)pa)[0];
    a1 = ((const float4*)pa)[1];
    a2 = ((const float4*)pa)[2];
    a3 = ((const float4*)pa)[3];
    const float* pb = Bm + (size_t)(k0 + r) * Nn + (bj * 64 + q4);
    b0 = ((const float4*)pb)[0];
    b1 = ((const float4*)pb)[1];
    b2 = ((const float4*)pb)[2];
    b3 = ((const float4*)pb)[3];
  };
  auto stagek = [&](int buf) {
    int4v p0 = {cvtpk(a0.x,a0.y), cvtpk(a0.z,a0.w), cvtpk(a1.x,a1.y), cvtpk(a1.z,a1.w)};
    int4v p1 = {cvtpk(a2.x,a2.y), cvtpk(a2.z,a2.w), cvtpk(a3.x,a3.y), cvtpk(a3.z,a3.w)};
    *(int4v*)&As[buf][r][q4]     = p0;
    *(int4v*)&As[buf][r][q4 + 8] = p1;
    Bs[buf][q4+ 0][r] = f2bf(b0.x); Bs[buf][q4+ 1][r] = f2bf(b0.y);
    Bs[buf][q4+ 2][r] = f2bf(b0.z); Bs[buf][q4+ 3][r] = f2bf(b0.w);
    Bs[buf][q4+ 4][r] = f2bf(b1.x); Bs[buf][q4+ 5][r] = f2bf(b1.y);
    Bs[buf][q4+ 6][r] = f2bf(b1.z); Bs[buf][q4+ 7][r] = f2bf(b1.w);
    Bs[buf][q4+ 8][r] = f2bf(b2.x); Bs[buf][q4+ 9][r] = f2bf(b2.y);
    Bs[buf][q4+10][r] = f2bf(b2.z); Bs[buf][q4+11][r] = f2bf(b2.w);
    Bs[buf][q4+12][r] = f2bf(b3.x); Bs[buf][q4+13][r] = f2bf(b3.y);
    Bs[buf][q4+14][r] = f2bf(b3.z); Bs[buf][q4+15][r] = f2bf(b3.w);
  };

  const int nk = K >> 6;
  loadk(0);
  stagek(0);
  if (nk > 1) loadk(64);
  ldsbar();

  for (int ki = 0; ki < nk; ++ki) {
    const int cur = ki & 1;
    #pragma unroll
    for (int kf = 0; kf < 2; ++kf) {
      short8 af[2], bfv[2];
      #pragma unroll
      for (int mt = 0; mt < 2; ++mt)
        af[mt] = *(const short8*)&As[cur][wm*32 + mt*16 + l16][kf*32 + g*8];
      #pragma unroll
      for (int nt = 0; nt < 2; ++nt)
        bfv[nt] = *(const short8*)&Bs[cur][wn*32 + nt*16 + l16][kf*32 + g*8];
      #pragma unroll
      for (int mt = 0; mt < 2; ++mt)
        #pragma unroll
        for (int nt = 0; nt < 2; ++nt)
          acc[mt][nt] = __builtin_amdgcn_mfma_f32_16x16x32_bf16(
              af[mt], bfv[nt], acc[mt][nt], 0, 0, 0);
    }
    if (ki + 1 < nk) {
      stagek(1 - cur);
      if (ki + 2 < nk) loadk((ki + 2) << 6);
      ldsbar();
    }
  }

  #pragma unroll
  for (int mt = 0; mt < 2; ++mt)
    #pragma unroll
    for (int nt = 0; nt < 2; ++nt)
      #pragma unroll
      for (int rg = 0; rg < 4; ++rg) {
        int row = bi*64 + wm*32 + mt*16 + g*4 + rg;
        int col = bj*64 + wn*32 + nt*16 + l16;
        float val = acc[mt][nt][rg] + bias[col];
        int which = col >> 10, cc = col & 1023;
        int h = cc >> 6, d = cc & 63;
        int b = row >> 8, n = row & 255;
        size_t idx = (((size_t)(b*NH + h))*NQ + n)*HD + d;
        if (which == 0)      qbuf[idx] = f2bf(val * 0.180336878f); // 0.125*log2(e)
        else if (which == 1) knew[idx] = val;
        else                 vnew[idx] = val;
      }
}

// ---------------------------------------------------------------------------
// Output projection GEMM: A is ALREADY bf16 (written by combine_k), B f32.
// A-staging = two short8 copies (no cvtpk). Cout = acc + bias, f32.
// ---------------------------------------------------------------------------
__global__ __launch_bounds__(256, 2) void gemm0_k(
    const short* __restrict__ Abf, const float* __restrict__ Bm,
    const float* __restrict__ bias, float* __restrict__ Cout,
    int M, int Nn, int K)
{
  __shared__ alignas(16) short As[2][64][72];
  __shared__ alignas(16) short Bs[2][64][72];
  const int tid = threadIdx.x;
  const int lane = tid & 63, wave = tid >> 6;
  const int nblk = Nn >> 6;
  const int bi = blockIdx.x / nblk, bj = blockIdx.x % nblk;
  const int wm = wave >> 1, wn = wave & 1;
  const int g = lane >> 4, l16 = lane & 15;
  f32x4 acc[2][2] = {};
  const int r = tid >> 2, q4 = (tid & 3) << 4;

  short8 av0, av1;
  float4 b0, b1, b2, b3;
  auto loadk = [&](int k0) {
    const short* pa = Abf + (size_t)(bi * 64 + r) * K + (k0 + q4);
    av0 = *(const short8*)pa;
    av1 = *(const short8*)(pa + 8);
    const float* pb = Bm + (size_t)(k0 + r) * Nn + (bj * 64 + q4);
    b0 = ((const float4*)pb)[0];
    b1 = ((const float4*)pb)[1];
    b2 = ((const float4*)pb)[2];
    b3 = ((const float4*)pb)[3];
  };
  auto stagek = [&](int buf) {
    *(short8*)&As[buf][r][q4]     = av0;
    *(short8*)&As[buf][r][q4 + 8] = av1;
    Bs[buf][q4+ 0][r] = f2bf(b0.x); Bs[buf][q4+ 1][r] = f2bf(b0.y);
    Bs[buf][q4+ 2][r] = f2bf(b0.z); Bs[buf][q4+ 3][r] = f2bf(b0.w);
    Bs[buf][q4+ 4][r] = f2bf(b1.x); Bs[buf][q4+ 5][r] = f2bf(b1.y);
    Bs[buf][q4+ 6][r] = f2bf(b1.z); Bs[buf][q4+ 7][r] = f2bf(b1.w);
    Bs[buf][q4+ 8][r] = f2bf(b2.x); Bs[buf][q4+ 9][r] = f2bf(b2.y);
    Bs[buf][q4+10][r] = f2bf(b2.z); Bs[buf][q4+11][r] = f2bf(b2.w);
    Bs[buf][q4+12][r] = f2bf(b3.x); Bs[buf][q4+13][r] = f2bf(b3.y);
    Bs[buf][q4+14][r] = f2bf(b3.z); Bs[buf][q4+15][r] = f2bf(b3.w);
  };

  const int nk = K >> 6;
  loadk(0);
  stagek(0);
  if (nk > 1) loadk(64);
  ldsbar();

  for (int ki = 0; ki < nk; ++ki) {
    const int cur = ki & 1;
    #pragma unroll
    for (int kf = 0; kf < 2; ++kf) {
      short8 af[2], bfv[2];
      #pragma unroll
      for (int mt = 0; mt < 2; ++mt)
        af[mt] = *(const short8*)&As[cur][wm*32 + mt*16 + l16][kf*32 + g*8];
      #pragma unroll
      for (int nt = 0; nt < 2; ++nt)
        bfv[nt] = *(const short8*)&Bs[cur][wn*32 + nt*16 + l16][kf*32 + g*8];
      #pragma unroll
      for (int mt = 0; mt < 2; ++mt)
        #pragma unroll
        for (int nt = 0; nt < 2; ++nt)
          acc[mt][nt] = __builtin_amdgcn_mfma_f32_16x16x32_bf16(
              af[mt], bfv[nt], acc[mt][nt], 0, 0, 0);
    }
    if (ki + 1 < nk) {
      stagek(1 - cur);
      if (ki + 2 < nk) loadk((ki + 2) << 6);
      ldsbar();
    }
  }

  #pragma unroll
  for (int mt = 0; mt < 2; ++mt)
    #pragma unroll
    for (int nt = 0; nt < 2; ++nt)
      #pragma unroll
      for (int rg = 0; rg < 4; ++rg) {
        int row = bi*64 + wm*32 + mt*16 + g*4 + rg;
        int col = bj*64 + wn*32 + nt*16 + l16;
        Cout[(size_t)row * Nn + col] = acc[mt][nt][rg] + bias[col];
      }
}

// ---------------------------------------------------------------------------
// Flash attention, split-KV, swapped-QK in-register softmax (exp2 domain).
// Grid: (B*H)*NSPLIT blocks, 256 threads = 4 waves x 64 queries each.
// Pipeline per iteration it: [QK(it) || PV(it-1)] 32-MFMA cluster ->
// stage(it+1) -> softmax(it)+pack(pa) -> ldsbar.  K buf = it&1, V buf = it%3.
// (== R14/R16, the best-measured attn variant)
// ---------------------------------------------------------------------------
__global__ __launch_bounds__(256, 2) void attn_k(
    const short* __restrict__ qbuf, const float* __restrict__ pastk,
    const float* __restrict__ pastv, const float* __restrict__ knew,
    const float* __restrict__ vnew, _Float16* __restrict__ opart,
    float* __restrict__ mbuf, float* __restrict__ lbuf)
{
  __shared__ alignas(16) short Kt[2][64][64];   // [buf][key][d], swizzled
  __shared__ alignas(16) short Vt[3][64][64];   // [buf][d][pi(key)], swizzled
  const int tid = threadIdx.x;
  const int lane = tid & 63, qg = tid >> 6;        // query group 0..3
  const int h = lane >> 5, c = lane & 31;
  const int s = blockIdx.x & (NSPLIT - 1), bh = blockIdx.x / NSPLIT;
  const int kr = tid >> 2, kd16 = (tid & 3) << 4;  // K staging: key kr, d kd16..+15
  const int vq2 = tid & 31, dg = tid >> 5;         // V staging: keys 2vq2,2vq2+1; d[8dg,+8)
  const int key0 = 2 * vq2;
  const int vpi = ((key0>>5)<<5) | (((key0>>3)&1)<<4) | (((key0>>2)&1)<<3)
                | (((key0>>4)&1)<<2) | (key0&3);   // pi(key0), even
  const int csw = (c & 7) << 3;                    // read-side swizzle term

  // Q fragments: lane holds Q[q][d = 16*dk + 8h + 0..7] for both tiles
  short8 qfA[4], qfB[4];
  #pragma unroll
  for (int dk = 0; dk < 4; ++dk) {
    qfA[dk] = *(const short8*)(qbuf + ((size_t)bh*NQ + qg*64 + c)*HD + 16*dk + 8*h);
    qfB[dk] = *(const short8*)(qbuf + ((size_t)bh*NQ + qg*64 + 32 + c)*HD + 16*dk + 8*h);
  }

  f32x16 accA[2] = {}, accB[2] = {};  // [dt]: O[q=rr][d=32*dt+c]
  float mA = -INFINITY, lA = 0.f, mB = -INFINITY, lB = 0.f;  // l = half-sums
  short8 paA[4], paB[4];              // P fragments of the PREVIOUS tile

  const int first  = 8*s + (s < 4 ? s : 4);
  const int nsteps = 8 + (s < 4 ? 1 : 0);

  float kst[16], vAr[8], vBr[8];
  auto load = [&](int step) {
    const float* kp = (step < 128)
        ? pastk + ((size_t)bh*LPAST + step*64 + kr)*HD + kd16
        : knew  + ((size_t)bh*NQ + (step - 128)*64 + kr)*HD + kd16;
    *(float4*)&kst[0]  = ((const float4*)kp)[0];
    *(float4*)&kst[4]  = ((const float4*)kp)[1];
    *(float4*)&kst[8]  = ((const float4*)kp)[2];
    *(float4*)&kst[12] = ((const float4*)kp)[3];
    const float* vq = (step < 128)
        ? pastv + ((size_t)bh*LPAST + step*64 + key0)*HD + 8*dg
        : vnew  + ((size_t)bh*NQ + (step - 128)*64 + key0)*HD + 8*dg;
    *(float4*)&vAr[0] = ((const float4*)vq)[0];        // key0,   d 8dg..+3
    *(float4*)&vAr[4] = ((const float4*)vq)[1];        // key0,   d 8dg+4..+7
    *(float4*)&vBr[0] = ((const float4*)(vq + HD))[0]; // key0+1, d 8dg..+3
    *(float4*)&vBr[4] = ((const float4*)(vq + HD))[1]; // key0+1, d 8dg+4..+7
  };
  // stage tile with iteration index it2 into Kt[it2&1], Vt[it2%3]
  auto stage_for = [&](int it2) {
    int kb = it2 & 1, vb = it2 % 3;
    int4v k0 = {cvtpk(kst[0],kst[1]),  cvtpk(kst[2],kst[3]),
                cvtpk(kst[4],kst[5]),  cvtpk(kst[6],kst[7])};
    int4v k1 = {cvtpk(kst[8],kst[9]),  cvtpk(kst[10],kst[11]),
                cvtpk(kst[12],kst[13]), cvtpk(kst[14],kst[15])};
    *(int4v*)&Kt[kb][kr][kd16 ^ ((kr & 7) << 3)]       = k0;
    *(int4v*)&Kt[kb][kr][(kd16 + 8) ^ ((kr & 7) << 3)] = k1;
    #pragma unroll
    for (int i = 0; i < 8; ++i) {
      int row = 8*dg + i;                            // row&7 == i
      *(int*)&Vt[vb][row][vpi ^ (i << 3)] = cvtpk(vAr[i], vBr[i]);
    }
  };

  load(first);
  stage_for(0);
  if (nsteps > 1) load(first + 1);
  ldsbar();

  for (int it = 0; it < nsteps; ++it) {
    const int kb = it & 1;

    // ---- merged MFMA cluster: QK(it) and deferred PV(it-1), all independent
    f32x16 svA0 = {}, svA1 = {}, svB0 = {}, svB1 = {};
    __builtin_amdgcn_s_setprio(1);
    if (it > 0) {
      const int pvb = (it - 1) % 3;
      #pragma unroll
      for (int kc = 0; kc < 4; ++kc) {
        #pragma unroll
        for (int dt = 0; dt < 2; ++dt) {
          short8 vf = *(const short8*)&Vt[pvb][32*dt + c][(16*kc + 8*h) ^ csw];
          accA[dt] = __builtin_amdgcn_mfma_f32_32x32x16_bf16(paA[kc], vf, accA[dt], 0,0,0);
          accB[dt] = __builtin_amdgcn_mfma_f32_32x32x16_bf16(paB[kc], vf, accB[dt], 0,0,0);
        }
      }
    }
    #pragma unroll
    for (int dk = 0; dk < 4; ++dk) {
      short8 k0 = *(const short8*)&Kt[kb][c][(16*dk + 8*h) ^ csw];
      svA0 = __builtin_amdgcn_mfma_f32_32x32x16_bf16(k0, qfA[dk], svA0, 0,0,0);
      svB0 = __builtin_amdgcn_mfma_f32_32x32x16_bf16(k0, qfB[dk], svB0, 0,0,0);
    }
    #pragma unroll
    for (int dk = 0; dk < 4; ++dk) {
      short8 k1 = *(const short8*)&Kt[kb][32 + c][(16*dk + 8*h) ^ csw];
      svA1 = __builtin_amdgcn_mfma_f32_32x32x16_bf16(k1, qfA[dk], svA1, 0,0,0);
      svB1 = __builtin_amdgcn_mfma_f32_32x32x16_bf16(k1, qfB[dk], svB1, 0,0,0);
    }
    __builtin_amdgcn_s_setprio(0);

    // ---- stage tile it+1, issue loads for it+2 (overlaps softmax below)
    if (it + 1 < nsteps) {
      stage_for(it + 1);
      if (it + 2 < nsteps) load(first + it + 2);
    }

    // ---- softmax tile A (rescale covers the just-landed PV(it-1)) ----
    {
      float t16[16];
      #pragma unroll
      for (int r = 0; r < 16; ++r) t16[r] = fmaxf(svA0[r], svA1[r]);
      #pragma unroll
      for (int w = 8; w >= 1; w >>= 1)
        #pragma unroll
        for (int r = 0; r < w; ++r) t16[r] = fmaxf(t16[r], t16[r + w]);
      if (!__all(t16[0] <= mA + 8.f)) {   // T13 defer-max
        float mx = fmaxf(t16[0], __shfl_xor(t16[0], 32));
        float mn = fmaxf(mA, mx);
        float al = exp2g(mA - mn);
        lA *= al;
        #pragma unroll
        for (int r = 0; r < 16; ++r) {
          float a = __shfl(al, (r&3) + 8*(r>>2) + 4*h);
          accA[0][r] *= a; accA[1][r] *= a;
        }
        mA = mn;
      }
      float ss = 0.f;
      #pragma unroll
      for (int r = 0; r < 16; ++r) {
        float p0 = exp2g(svA0[r] - mA); svA0[r] = p0;
        float p1 = exp2g(svA1[r] - mA); svA1[r] = p1;
        ss += p0 + p1;
      }
      lA += ss;
      #pragma unroll
      for (int kc = 0; kc < 4; ++kc) {
        int4v w;
        #pragma unroll
        for (int jd = 0; jd < 4; ++jd) {
          int r0 = 8*(jd>>1) + 4*(kc&1) + 2*(jd&1);
          w[jd] = (kc < 2) ? cvtpk(svA0[r0], svA0[r0+1])
                           : cvtpk(svA1[r0], svA1[r0+1]);
        }
        paA[kc] = __builtin_bit_cast(short8, w);
      }
    }
    // ---- softmax tile B ----
    {
      float t16[16];
      #pragma unroll
      for (int r = 0; r < 16; ++r) t16[r] = fmaxf(svB0[r], svB1[r]);
      #pragma unroll
      for (int w = 8; w >= 1; w >>= 1)
        #pragma unroll
        for (int r = 0; r < w; ++r) t16[r] = fmaxf(t16[r], t16[r + w]);
      if (!__all(t16[0] <= mB + 8.f)) {
        float mx = fmaxf(t16[0], __shfl_xor(t16[0], 32));
        float mn = fmaxf(mB, mx);
        float al = exp2g(mB - mn);
        lB *= al;
        #pragma unroll
        for (int r = 0; r < 16; ++r) {
          float a = __shfl(al, (r&3) + 8*(r>>2) + 4*h);
          accB[0][r] *= a; accB[1][r] *= a;
        }
        mB = mn;
      }
      float ss = 0.f;
      #pragma unroll
      for (int r = 0; r < 16; ++r) {
        float p0 = exp2g(svB0[r] - mB); svB0[r] = p0;
        float p1 = exp2g(svB1[r] - mB); svB1[r] = p1;
        ss += p0 + p1;
      }
      lB += ss;
      #pragma unroll
      for (int kc = 0; kc < 4; ++kc) {
        int4v w;
        #pragma unroll
        for (int jd = 0; jd < 4; ++jd) {
          int r0 = 8*(jd>>1) + 4*(kc&1) + 2*(jd&1);
          w[jd] = (kc < 2) ? cvtpk(svB0[r0], svB0[r0+1])
                           : cvtpk(svB1[r0], svB1[r0+1]);
        }
        paB[kc] = __builtin_bit_cast(short8, w);
      }
    }

    if (it + 1 < nsteps) ldsbar();
  }

  // ---- epilogue: final deferred PV for tile nsteps-1
  {
    const int pvb = (nsteps - 1) % 3;
    #pragma unroll
    for (int kc = 0; kc < 4; ++kc) {
      #pragma unroll
      for (int dt = 0; dt < 2; ++dt) {
        short8 vf = *(const short8*)&Vt[pvb][32*dt + c][(16*kc + 8*h) ^ csw];
        accA[dt] = __builtin_amdgcn_mfma_f32_32x32x16_bf16(paA[kc], vf, accA[dt], 0,0,0);
        accB[dt] = __builtin_amdgcn_mfma_f32_32x32x16_bf16(paB[kc], vf, accB[dt], 0,0,0);
      }
    }
  }

  // Write NORMALIZED partials (o/l as f16). acc[dt][r] is query rr's row, so
  // fetch that query's reciprocal from lane rr (R12 fix).
  float lAt = lA + __shfl_xor(lA, 32);
  float lBt = lB + __shfl_xor(lB, 32);
  float rA = 1.0f / lAt, rB = 1.0f / lBt;
  size_t pbase = ((size_t)(bh * NSPLIT + s)) * NQ;
  #pragma unroll
  for (int r = 0; r < 16; ++r) {
    int rr = (r&3) + 8*(r>>2) + 4*h;
    float rAr = __shfl(rA, rr);     // lane rr owns query rr's l (tile A)
    float rBr = __shfl(rB, rr);     // lane rr owns query 32+rr's l (tile B)
    #pragma unroll
    for (int dt = 0; dt < 2; ++dt) {
      opart[(pbase + qg*64 + rr)*HD + 32*dt + c]      = (_Float16)(accA[dt][r] * rAr);
      opart[(pbase + qg*64 + 32 + rr)*HD + 32*dt + c] = (_Float16)(accB[dt][r] * rBr);
    }
  }
  if (lane < 32) {
    mbuf[pbase + qg*64 + c]      = mA;
    lbuf[pbase + qg*64 + c]      = lAt;
    mbuf[pbase + qg*64 + 32 + c] = mB;
    lbuf[pbase + qg*64 + 32 + c] = lBt;
  }
}

// ---------------------------------------------------------------------------
// Combine NSPLIT partials per (b,h,n); write attn output [B,N,DIM] as BF16
// (the proj GEMM quantized A to bf16 anyway -- identical numerics).
// Partials are normalized (o/l), so weight = l * 2^(m-M).
// ---------------------------------------------------------------------------
__global__ __launch_bounds__(256) void combine_k(
    const _Float16* __restrict__ opart, const float* __restrict__ mbuf,
    const float* __restrict__ lbuf, short* __restrict__ attnout)
{
  const int lane = threadIdx.x & 63, wave = threadIdx.x >> 6;
  const int rid = blockIdx.x * 4 + wave;   // 0 .. B*H*N-1
  const int bh = rid >> 8, n = rid & 255;
  const int b = bh >> 4, h = bh & 15;
  float M = -INFINITY;
  float ms[NSPLIT], ls[NSPLIT];
  #pragma unroll
  for (int s = 0; s < NSPLIT; ++s) {
    size_t base = ((size_t)(bh * NSPLIT + s)) * NQ + n;
    ms[s] = mbuf[base]; ls[s] = lbuf[base];
    M = fmaxf(M, ms[s]);
  }
  float denom = 0.f, o = 0.f;
  #pragma unroll
  for (int s = 0; s < NSPLIT; ++s) {
    float w = exp2g(ms[s] - M) * ls[s];
    denom += w;
    o += w * (float)opart[(((size_t)(bh * NSPLIT + s)) * NQ + n) * HD + lane];
  }
  attnout[((size_t)(b * NQ + n)) * DIMC + h * HD + lane] = f2bf(o / denom);
}

// ---------------------------------------------------------------------------
extern "C" void kernel_launch(void* const* d_in, const int* in_sizes, int n_in,
                              void* d_out, int out_size, void* d_ws, size_t ws_size,
                              hipStream_t stream)
{
  const float* x     = (const float*)d_in[0];
  const float* pastk = (const float*)d_in[1];
  const float* pastv = (const float*)d_in[2];
  const float* wqkv  = (const float*)d_in[3];
  const float* bqkv  = (const float*)d_in[4];
  const float* wproj = (const float*)d_in[5];
  const float* bproj = (const float*)d_in[6];
  float* out = (float*)d_out;
  char* ws = (char*)d_ws;

  size_t off = 0;
  short* qbuf     = (short*)(ws + off);     off += (size_t)BB*NH*NQ*HD*2;          // 1MB
  float* knew     = (float*)(ws + off);     off += (size_t)BB*NH*NQ*HD*4;          // 2MB
  float* vnew     = (float*)(ws + off);     off += (size_t)BB*NH*NQ*HD*4;          // 2MB
  _Float16* opart = (_Float16*)(ws + off);  off += (size_t)BB*NH*NSPLIT*NQ*HD*2;   // 16.8MB
  float* mbuf     = (float*)(ws + off);     off += (size_t)BB*NH*NSPLIT*NQ*4;      // 512KB
  float* lbuf     = (float*)(ws + off);     off += (size_t)BB*NH*NSPLIT*NQ*4;      // 512KB
  short* attnout  = (short*)(ws + off);     off += (size_t)BB*NQ*DIMC*2;           // 1MB

  // 1) QKV projection: [512,1024] x [1024,3072]
  gemm_k<<<(512/64)*(3072/64), 256, 0, stream>>>(
      x, wqkv, bqkv, qbuf, knew, vnew, 512, 3072, 1024);
  // 2) split-KV flash attention
  attn_k<<<BB*NH*NSPLIT, 256, 0, stream>>>(
      qbuf, pastk, pastv, knew, vnew, opart, mbuf, lbuf);
  // 3) combine partials -> bf16 attn output
  combine_k<<<BB*NH*NQ/4, 256, 0, stream>>>(opart, mbuf, lbuf, attnout);
  // 4) output projection: [512,1024](bf16) x [1024,1024](f32)
  gemm0_k<<<(512/64)*(1024/64), 256, 0, stream>>>(
      attnout, wproj, bproj, out, 512, 1024, 1024);
}